// Round 1
// baseline (4020.345 us; speedup 1.0000x reference)
//
#include <hip/hip_runtime.h>
#include <math.h>

// ---------------------------------------------------------------------------
// CapsNet forward, fp32 baseline (correctness-first).
// conv1: [256,1,28,28] -> [256,256,20,20] (9x9, VALID, +bias, ReLU)
// conv2: [256,256,20,20] -> [256,256,6,6] (9x9, stride2, VALID, +bias)
// primary squash (scale = sq/(1+sq))  -> ut[n][j][b]  (n=1152, j=8, b=256)
// routing (3 iters), probs are batch-independent -> never materialize u_hat.
// ---------------------------------------------------------------------------

#define NB_TOT 256      // batch
#define NCAPS 1152
#define NCLS 10

// workspace offsets (in floats)
static const size_t OFF_H1 = 0;                         // [256][256][400]  26,214,400
static const size_t OFF_H2 = 26214400;                  // [256][9216]       2,359,296
static const size_t OFF_UT = OFF_H2 + 2359296;          // [1152][8][256]    2,359,296
static const size_t OFF_SP = OFF_UT + 2359296;          // [36][160][256]    1,474,560
static const size_t OFF_O  = OFF_SP + 1474560;          // [160][256]           40,960
static const size_t OFF_BS = OFF_O  + 40960;            // [10][1152][16]      184,320
static const size_t OFF_PR = OFF_BS + 184320;           // [10][1152][16]      184,320
static const size_t WS_FLOATS = OFF_PR + 184320;        // 32,817,152 floats ~ 131.3 MB

// ---------------- conv1: block = (ctile of 16, batch) ----------------------
__global__ __launch_bounds__(256) void conv1_kernel(
        const float* __restrict__ x, const float* __restrict__ w,
        const float* __restrict__ bias, float* __restrict__ h1) {
    int ct = blockIdx.x;      // 0..15
    int b  = blockIdx.y;      // 0..255
    int c0 = ct * 16;
    __shared__ float xs[784];
    for (int idx = threadIdx.x; idx < 784; idx += 256) xs[idx] = x[(size_t)b*784 + idx];
    __syncthreads();
    for (int p = threadIdx.x; p < 400; p += 256) {
        int oy = p / 20, ox = p % 20;
        float acc[16];
        #pragma unroll
        for (int c = 0; c < 16; ++c) acc[c] = bias[c0 + c];
        for (int ky = 0; ky < 9; ++ky) {
            int rb = (oy + ky) * 28 + ox;
            #pragma unroll
            for (int kx = 0; kx < 9; ++kx) {
                float xv = xs[rb + kx];
                #pragma unroll
                for (int c = 0; c < 16; ++c)      // w index is thread-uniform -> s_load
                    acc[c] = fmaf(xv, w[(c0 + c) * 81 + ky * 9 + kx], acc[c]);
            }
        }
        #pragma unroll
        for (int c = 0; c < 16; ++c)
            h1[(size_t)b*102400 + (size_t)(c0 + c)*400 + p] = fmaxf(acc[c], 0.0f);
    }
}

// ---------------- conv2: block = (ctile 32, btile 8), thread = 4c x 9pos ----
__global__ __launch_bounds__(256) void conv2_kernel(
        const float* __restrict__ h1, const float* __restrict__ w,
        const float* __restrict__ bias, float* __restrict__ h2) {
    int ct = blockIdx.x;               // 0..7   (32 c_out each)
    int bt = blockIdx.y;               // 0..31  (8 batches each)
    int c0 = ct * 32, b0 = bt * 8;
    int t  = threadIdx.x;
    int cg = t & 7;                    // 8 channel groups (x4 channels)
    int pg = (t >> 3) & 3;             // 4 position groups (x9 positions)
    int bl = t >> 5;                   // 0..7 local batch

    __shared__ float xs[3200];         // 8 batches x 400
    __shared__ float wsm[81][32];      // [k][c_local]

    int boff[9];
    int pbase = pg * 9;
    #pragma unroll
    for (int e = 0; e < 9; ++e) {
        int p = pbase + e; int oy = p / 6, ox = p % 6;
        boff[e] = bl * 400 + oy * 40 + ox * 2;
    }
    float acc[4][9];
    #pragma unroll
    for (int cc = 0; cc < 4; ++cc)
        #pragma unroll
        for (int e = 0; e < 9; ++e) acc[cc][e] = 0.0f;

    for (int ci = 0; ci < 256; ++ci) {
        __syncthreads();
        for (int idx = t; idx < 3200; idx += 256) {
            int bb = idx / 400; int p = idx - bb * 400;
            xs[idx] = h1[(size_t)(b0 + bb)*102400 + (size_t)ci*400 + p];
        }
        for (int idx = t; idx < 2592; idx += 256) {
            int cc = idx / 81; int k = idx - cc * 81;
            wsm[k][cc] = w[(size_t)(c0 + cc)*20736 + (size_t)ci*81 + k];
        }
        __syncthreads();
        for (int ky = 0; ky < 9; ++ky) {
            #pragma unroll
            for (int kx = 0; kx < 9; ++kx) {
                int koff = ky * 20 + kx;
                int k = ky * 9 + kx;
                float4 wv = *(const float4*)&wsm[k][cg * 4];
                #pragma unroll
                for (int e = 0; e < 9; ++e) {
                    float xv = xs[boff[e] + koff];
                    acc[0][e] = fmaf(wv.x, xv, acc[0][e]);
                    acc[1][e] = fmaf(wv.y, xv, acc[1][e]);
                    acc[2][e] = fmaf(wv.z, xv, acc[2][e]);
                    acc[3][e] = fmaf(wv.w, xv, acc[3][e]);
                }
            }
        }
    }
    int b = b0 + bl;
    #pragma unroll
    for (int cc = 0; cc < 4; ++cc) {
        int c = c0 + cg * 4 + cc;
        float bv = bias[c];
        #pragma unroll
        for (int e = 0; e < 9; ++e) {
            int p = pbase + e;
            h2[(size_t)b*9216 + (size_t)c*36 + p] = acc[cc][e] + bv;
        }
    }
}

// -------- primary squash + transpose to ut[n][j][b] -------------------------
__global__ __launch_bounds__(256) void squash_t_kernel(
        const float* __restrict__ h2, float* __restrict__ ut) {
    int n = blockIdx.x;       // 0..1151
    int b = threadIdx.x;      // 0..255
    const float4* p = (const float4*)(h2 + (size_t)b*9216 + (size_t)n*8);
    float4 v0 = p[0], v1 = p[1];
    float sq = v0.x*v0.x + v0.y*v0.y + v0.z*v0.z + v0.w*v0.w
             + v1.x*v1.x + v1.y*v1.y + v1.z*v1.z + v1.w*v1.w;
    float sc = sq / (1.0f + sq);   // primary squash: NO /sqrt
    float vals[8] = {v0.x, v0.y, v0.z, v0.w, v1.x, v1.y, v1.z, v1.w};
    #pragma unroll
    for (int j = 0; j < 8; ++j)
        ut[((size_t)n*8 + j)*256 + b] = sc * vals[j];
}

// -------- s partials: s[c,i,b] = sum_n probs[c,n,i] * sum_j W*ut ------------
__global__ __launch_bounds__(256) void spart_kernel(
        const float* __restrict__ ut, const float* __restrict__ W,
        const float* __restrict__ probs, float* __restrict__ sp, int uniform) {
    int ch = blockIdx.x;      // 0..35 (n-chunks of 32)
    int c  = blockIdx.y;      // 0..9
    int t  = threadIdx.x;     // b
    float acc[16];
    #pragma unroll
    for (int i = 0; i < 16; ++i) acc[i] = 0.0f;
    int n0 = ch * 32;
    for (int nn = 0; nn < 32; ++nn) {
        int n = n0 + nn;
        float utv[8];
        #pragma unroll
        for (int j = 0; j < 8; ++j) utv[j] = ut[((size_t)n*8 + j)*256 + t];
        const float* Wr = W + ((size_t)c*1152 + n)*128;      // uniform -> s_load
        const float* pr = probs + ((size_t)c*1152 + n)*16;
        #pragma unroll
        for (int i = 0; i < 16; ++i) {
            float wsv = 0.0f;
            #pragma unroll
            for (int j = 0; j < 8; ++j) wsv = fmaf(Wr[i*8 + j], utv[j], wsv);
            float p = uniform ? (1.0f / 1152.0f) : pr[i];
            acc[i] = fmaf(p, wsv, acc[i]);
        }
    }
    #pragma unroll
    for (int i = 0; i < 16; ++i)
        sp[(size_t)ch*40960 + ((size_t)c*16 + i)*256 + t] = acc[i];
}

// -------- reduce partials + routing squash over batch axis ------------------
__global__ __launch_bounds__(256) void sreduce_kernel(
        const float* __restrict__ sp, float* __restrict__ obuf) {
    int ci = blockIdx.x;      // 0..159 = c*16+i
    int t  = threadIdx.x;     // b
    float s = 0.0f;
    for (int ch = 0; ch < 36; ++ch) s += sp[(size_t)ch*40960 + (size_t)ci*256 + t];
    float v = s * s;
    #pragma unroll
    for (int m = 1; m < 64; m <<= 1) v += __shfl_xor(v, m, 64);
    __shared__ float red[4];
    if ((t & 63) == 0) red[t >> 6] = v;
    __syncthreads();
    float total = red[0] + red[1] + red[2] + red[3];
    float sc = total / ((1.0f + total) * sqrtf(total));   // routing squash over b
    obuf[(size_t)ci*256 + t] = sc * s;
}

// -------- delta_b[c,n,i] = sum_b u_hat * outputs ; accumulate into bsum -----
__global__ __launch_bounds__(256) void delta_kernel(
        const float* __restrict__ ut, const float* __restrict__ W,
        const float* __restrict__ obuf, float* __restrict__ bsum, int first) {
    int ch = blockIdx.x;      // 0..35
    int c  = blockIdx.y;      // 0..9
    int t  = threadIdx.x;     // b
    float o16[16];
    #pragma unroll
    for (int i = 0; i < 16; ++i) o16[i] = obuf[((size_t)c*16 + i)*256 + t];
    __shared__ float vbuf[16][257];
    int ri = t >> 4, seg = t & 15;
    int n0 = ch * 32;
    for (int nn = 0; nn < 32; ++nn) {
        int n = n0 + nn;
        float utv[8];
        #pragma unroll
        for (int j = 0; j < 8; ++j) utv[j] = ut[((size_t)n*8 + j)*256 + t];
        const float* Wr = W + ((size_t)c*1152 + n)*128;
        #pragma unroll
        for (int i = 0; i < 16; ++i) {
            float uh = 0.0f;
            #pragma unroll
            for (int j = 0; j < 8; ++j) uh = fmaf(Wr[i*8 + j], utv[j], uh);
            vbuf[i][t] = uh * o16[i];
        }
        __syncthreads();
        float part = 0.0f;
        #pragma unroll
        for (int k = 0; k < 16; ++k) part += vbuf[ri][k*16 + seg];
        #pragma unroll
        for (int m = 1; m < 16; m <<= 1) part += __shfl_xor(part, m, 64);
        if (seg == 0) {
            size_t bi = ((size_t)c*1152 + n)*16 + ri;
            bsum[bi] = first ? part : (bsum[bi] + part);
        }
        __syncthreads();
    }
}

// -------- softmax over the 1152 capsule axis --------------------------------
__global__ __launch_bounds__(256) void softmax_kernel(
        const float* __restrict__ bsum, float* __restrict__ probs) {
    int ci = blockIdx.x;      // c*16+i
    int c = ci >> 4, i = ci & 15;
    int t = threadIdx.x;
    const float* bp = bsum + (size_t)c*1152*16 + i;
    float vals[5];
    float m = -1e30f;
    #pragma unroll
    for (int k = 0; k < 5; ++k) {
        int n = t + k * 256;
        vals[k] = (n < 1152) ? bp[(size_t)n*16] : -1e30f;
        m = fmaxf(m, vals[k]);
    }
    #pragma unroll
    for (int mm = 1; mm < 64; mm <<= 1) m = fmaxf(m, __shfl_xor(m, mm, 64));
    __shared__ float red[4];
    if ((t & 63) == 0) red[t >> 6] = m;
    __syncthreads();
    m = fmaxf(fmaxf(red[0], red[1]), fmaxf(red[2], red[3]));
    __syncthreads();
    float se = 0.0f;
    #pragma unroll
    for (int k = 0; k < 5; ++k) {
        int n = t + k * 256;
        float e = (n < 1152) ? expf(vals[k] - m) : 0.0f;
        vals[k] = e;
        se += e;
    }
    #pragma unroll
    for (int mm = 1; mm < 64; mm <<= 1) se += __shfl_xor(se, mm, 64);
    if ((t & 63) == 0) red[t >> 6] = se;
    __syncthreads();
    se = red[0] + red[1] + red[2] + red[3];
    float inv = 1.0f / se;
    #pragma unroll
    for (int k = 0; k < 5; ++k) {
        int n = t + k * 256;
        if (n < 1152) probs[((size_t)c*1152 + n)*16 + i] = vals[k] * inv;
    }
}

// -------- final: out[b,c] = sum_i outputs[c,i,b]^2 --------------------------
__global__ __launch_bounds__(256) void final_kernel(
        const float* __restrict__ obuf, float* __restrict__ out) {
    int c = blockIdx.x;       // 0..9
    int t = threadIdx.x;      // b
    float s = 0.0f;
    #pragma unroll
    for (int i = 0; i < 16; ++i) {
        float v = obuf[((size_t)c*16 + i)*256 + t];
        s = fmaf(v, v, s);
    }
    out[(size_t)t*10 + c] = s;
}

// ---------------------------------------------------------------------------
extern "C" void kernel_launch(void* const* d_in, const int* in_sizes, int n_in,
                              void* d_out, int out_size, void* d_ws, size_t ws_size,
                              hipStream_t stream) {
    const float* x  = (const float*)d_in[0];
    const float* w1 = (const float*)d_in[1];
    const float* b1 = (const float*)d_in[2];
    const float* w2 = (const float*)d_in[3];
    const float* b2 = (const float*)d_in[4];
    const float* W  = (const float*)d_in[5];
    float* out = (float*)d_out;

    if (ws_size < WS_FLOATS * sizeof(float)) return;  // ws too small: visible failure

    float* ws = (float*)d_ws;
    float* h1 = ws + OFF_H1;
    float* h2 = ws + OFF_H2;
    float* ut = ws + OFF_UT;
    float* sp = ws + OFF_SP;
    float* ob = ws + OFF_O;
    float* bs = ws + OFF_BS;
    float* pr = ws + OFF_PR;

    conv1_kernel<<<dim3(16, 256), 256, 0, stream>>>(x, w1, b1, h1);
    conv2_kernel<<<dim3(8, 32), 256, 0, stream>>>(h1, w2, b2, h2);
    squash_t_kernel<<<1152, 256, 0, stream>>>(h2, ut);

    for (int it = 0; it < 3; ++it) {
        if (it > 0) softmax_kernel<<<160, 256, 0, stream>>>(bs, pr);
        spart_kernel<<<dim3(36, 10), 256, 0, stream>>>(ut, W, pr, sp, it == 0 ? 1 : 0);
        sreduce_kernel<<<160, 256, 0, stream>>>(sp, ob);
        if (it < 2) delta_kernel<<<dim3(36, 10), 256, 0, stream>>>(ut, W, ob, bs, it == 0 ? 1 : 0);
    }
    final_kernel<<<10, 256, 0, stream>>>(ob, out);
}

// Round 2
// 1149.415 us; speedup vs baseline: 3.4977x; 3.4977x over previous
//
#include <hip/hip_runtime.h>
#include <math.h>

using short8 = __attribute__((ext_vector_type(8))) short;
using f32x4  = __attribute__((ext_vector_type(4))) float;

// ---------------- workspace byte offsets ----------------
// h1q (conv1 out, transposed [qy][qx][b][ci], bf16 hi/lo): 361*256*256 each
static const size_t B_QHI = 0;
static const size_t B_QLO = 47316992;
// w2t ([k][c][ci] bf16 hi/lo): 81*256*256 each
static const size_t B_WHI = 94633984;
static const size_t B_WLO = 105250816;
// h2 (conv2 out, [b][9216] fp32)
static const size_t B_H2  = 115867648;
static const size_t B_END = 125304832;   // 125.3 MB total (<131.3 known-good)
// routing buffers alias h1q region (dead after conv2) — float offsets from ws
static const size_t F_UT = 0;            // [1152][8][256]
static const size_t F_SP = 2359296;      // [36][160][256]
static const size_t F_OB = 3833856;      // [160][256]
static const size_t F_BS = 3874816;      // [10][1152][16]
static const size_t F_PR = 4059136;      // [10][1152][16]

__device__ __forceinline__ unsigned short bf16_rne(float v) {
    unsigned int u = __builtin_bit_cast(unsigned int, v);
    u += 0x7FFFu + ((u >> 16) & 1u);
    return (unsigned short)(u >> 16);
}
__device__ __forceinline__ float bf16_tof(unsigned short h) {
    unsigned int u = ((unsigned int)h) << 16;
    return __builtin_bit_cast(float, u);
}

// ---------------- conv1: block=b, thread=c; writes h1q hi/lo ----------------
__global__ __launch_bounds__(256) void conv1_kernel(
        const float* __restrict__ x, const float* __restrict__ w1,
        const float* __restrict__ b1,
        unsigned short* __restrict__ qhi, unsigned short* __restrict__ qlo) {
    int b = blockIdx.x;
    int c = threadIdx.x;
    __shared__ float xs[784];
    for (int i = c; i < 784; i += 256) xs[i] = x[(size_t)b*784 + i];
    float wr[81];
    #pragma unroll
    for (int k = 0; k < 81; ++k) wr[k] = w1[c*81 + k];
    float bias = b1[c];
    __syncthreads();
    // only positions [0,19)x[0,19) are consumed by conv2 (stride2, 9x9, 6x6 out)
    for (int qy = 0; qy < 19; ++qy) {
        for (int qx = 0; qx < 19; ++qx) {
            float a0 = 0.f, a1 = 0.f;   // two chains for ILP
            #pragma unroll
            for (int ky = 0; ky < 9; ++ky) {
                int rb = (qy + ky)*28 + qx;
                #pragma unroll
                for (int kx = 0; kx < 9; ++kx) {
                    float xv = xs[rb + kx];
                    if (ky < 5) a0 = fmaf(xv, wr[ky*9 + kx], a0);
                    else        a1 = fmaf(xv, wr[ky*9 + kx], a1);
                }
            }
            float v = fmaxf(bias + a0 + a1, 0.f);   // bias + ReLU
            unsigned short hi = bf16_rne(v);
            unsigned short lo = bf16_rne(v - bf16_tof(hi));
            size_t o = ((size_t)(qy*19 + qx)*256 + b)*256 + c;   // coalesced in c
            qhi[o] = hi; qlo[o] = lo;
        }
    }
}

// ---------------- w2 transpose+split: [c][ci][81] -> [k][c][ci] hi/lo -------
__global__ __launch_bounds__(256) void w2t_kernel(
        const float* __restrict__ w2,
        unsigned short* __restrict__ whi, unsigned short* __restrict__ wlo) {
    int c    = blockIdx.x;     // out channel
    int half = blockIdx.y;     // ci half (128 each)
    int t = threadIdx.x;
    __shared__ float buf[128*81];
    const float* src = w2 + (size_t)c*20736 + (size_t)half*128*81;
    for (int i = t; i < 128*81; i += 256) buf[i] = src[i];
    __syncthreads();
    int kk = t >> 7, cil = t & 127;
    for (int k2 = 0; k2 < 41; ++k2) {
        int k = k2*2 + kk;
        if (k < 81) {
            float v = buf[cil*81 + k];          // stride 81 (odd) = conflict-free
            unsigned short hi = bf16_rne(v);
            unsigned short lo = bf16_rne(v - bf16_tof(hi));
            size_t o = ((size_t)k*256 + c)*256 + half*128 + cil;  // coalesced in ci
            whi[o] = hi; wlo[o] = lo;
        }
    }
}

// ---------------- conv2 as implicit GEMM on MFMA ----------------------------
// out[b][c][oy*6+ox] = sum_{ci,ky,kx} h1q[2oy+ky][2ox+kx][b][ci] * w2t[ky*9+kx][c][ci]
// block: bt (16 b) x oy (fixed) x cg (32 c). 4 waves: (mh = ox-half, ch = c-half16).
// K-loop: (ky, cis): stage A-union [19 qx][16 b][32 ci] + B [9 kx][32 c][32 ci],
// hi+lo, into LDS with 16B-chunk XOR swizzle (2-way bank conflicts only).
__global__ __launch_bounds__(256, 2) void conv2_mfma(
        const unsigned short* __restrict__ qhi, const unsigned short* __restrict__ qlo,
        const unsigned short* __restrict__ whi, const unsigned short* __restrict__ wlo,
        const float* __restrict__ b2, float* __restrict__ h2) {
    int bx = blockIdx.x;            // 0..95
    int bt = bx / 6, oy = bx % 6;
    int cg = blockIdx.y;            // 0..7
    int t = threadIdx.x;
    int wv = t >> 6, l = t & 63;
    int mh = wv >> 1, ch = wv & 1;
    int r = l & 15, sl = l >> 4;
    int cs = sl ^ ((r >> 1) & 3);   // swizzled 16B-chunk index for frag reads

    __shared__ unsigned short Ah[9728], Al[9728];   // 19*16 rows x 32 ci
    __shared__ unsigned short Bh[9216], Bl[9216];   // 9*32 rows x 32 ci

    f32x4 acc[3];
    #pragma unroll
    for (int i = 0; i < 3; ++i) acc[i] = (f32x4){0.f, 0.f, 0.f, 0.f};

    for (int ky = 0; ky < 9; ++ky) {
        int qy = oy*2 + ky;
        for (int cis = 0; cis < 8; ++cis) {
            __syncthreads();
            // ---- stage A: 1216 hi + 1216 lo 16B-chunks
            for (int i = 0; i < 10; ++i) {
                int idx = i*256 + t;
                if (idx < 2432) {
                    int isLo = idx >= 1216;
                    int chk = isLo ? idx - 1216 : idx;
                    int row = chk >> 2, s = chk & 3;
                    int qx = row >> 4, bb = row & 15;
                    const unsigned short* src = isLo ? qlo : qhi;
                    size_t g = ((size_t)((qy*19 + qx)*256) + bt*16 + bb)*256
                             + (size_t)cis*32 + s*8;
                    short8 v = *(const short8*)(src + g);
                    unsigned short* dst = isLo ? Al : Ah;
                    int ss = s ^ ((row >> 1) & 3);
                    *(short8*)(dst + row*32 + ss*8) = v;
                }
            }
            // ---- stage B: 1152 hi + 1152 lo chunks (exactly 9*256)
            for (int i = 0; i < 9; ++i) {
                int idx = i*256 + t;
                int isLo = idx >= 1152;
                int chk = isLo ? idx - 1152 : idx;
                int row = chk >> 2, s = chk & 3;
                int kx = row >> 5, cl = row & 31;
                const unsigned short* src = isLo ? wlo : whi;
                size_t g = ((size_t)((ky*9 + kx)*256) + cg*32 + cl)*256
                         + (size_t)cis*32 + s*8;
                short8 v = *(const short8*)(src + g);
                unsigned short* dst = isLo ? Bl : Bh;
                int ss = s ^ ((row >> 1) & 3);
                *(short8*)(dst + row*32 + ss*8) = v;
            }
            __syncthreads();
            // ---- hoist A-frags (13 qx values per ox-half), static-indexed
            short8 afh[13], afl[13];
            #pragma unroll
            for (int ql = 0; ql < 13; ++ql) {
                int off = ((mh*6 + ql)*16 + r)*32 + cs*8;
                afh[ql] = *(const short8*)(Ah + off);
                afl[ql] = *(const short8*)(Al + off);
            }
            // ---- MFMA: 9 kx x 3 ox x 3 split-products
            #pragma unroll
            for (int kx = 0; kx < 9; ++kx) {
                int boff = (kx*32 + ch*16 + r)*32 + cs*8;
                short8 bhv = *(const short8*)(Bh + boff);
                short8 blv = *(const short8*)(Bl + boff);
                #pragma unroll
                for (int oxl = 0; oxl < 3; ++oxl) {
                    int ql = 2*oxl + kx;          // compile-time (both unrolled)
                    acc[oxl] = __builtin_amdgcn_mfma_f32_16x16x32_bf16(afh[ql], bhv, acc[oxl], 0, 0, 0);
                    acc[oxl] = __builtin_amdgcn_mfma_f32_16x16x32_bf16(afh[ql], blv, acc[oxl], 0, 0, 0);
                    acc[oxl] = __builtin_amdgcn_mfma_f32_16x16x32_bf16(afl[ql], bhv, acc[oxl], 0, 0, 0);
                }
            }
        }
    }
    // ---- epilogue: C/D layout col=l&15, row=(l>>4)*4+reg
    int cglob = cg*32 + ch*16 + r;
    float bv = b2[cglob];
    #pragma unroll
    for (int oxl = 0; oxl < 3; ++oxl) {
        int p = oy*6 + mh*3 + oxl;
        #pragma unroll
        for (int reg = 0; reg < 4; ++reg) {
            int bb = bt*16 + sl*4 + reg;
            h2[(size_t)bb*9216 + cglob*36 + p] = acc[oxl][reg] + bv;
        }
    }
}

// -------- primary squash + transpose to ut[n][j][b] -------------------------
__global__ __launch_bounds__(256) void squash_t_kernel(
        const float* __restrict__ h2, float* __restrict__ ut) {
    int n = blockIdx.x;       // 0..1151
    int b = threadIdx.x;      // 0..255
    const float4* p = (const float4*)(h2 + (size_t)b*9216 + (size_t)n*8);
    float4 v0 = p[0], v1 = p[1];
    float sq = v0.x*v0.x + v0.y*v0.y + v0.z*v0.z + v0.w*v0.w
             + v1.x*v1.x + v1.y*v1.y + v1.z*v1.z + v1.w*v1.w;
    float sc = sq / (1.0f + sq);   // primary squash: NO /sqrt
    float vals[8] = {v0.x, v0.y, v0.z, v0.w, v1.x, v1.y, v1.z, v1.w};
    #pragma unroll
    for (int j = 0; j < 8; ++j)
        ut[((size_t)n*8 + j)*256 + b] = sc * vals[j];
}

// -------- s partials: s[c,i,b] = sum_n probs[c,n,i] * sum_j W*ut ------------
__global__ __launch_bounds__(256) void spart_kernel(
        const float* __restrict__ ut, const float* __restrict__ W,
        const float* __restrict__ probs, float* __restrict__ sp, int uniform) {
    int ch = blockIdx.x;      // 0..35 (n-chunks of 32)
    int c  = blockIdx.y;      // 0..9
    int t  = threadIdx.x;     // b
    float acc[16];
    #pragma unroll
    for (int i = 0; i < 16; ++i) acc[i] = 0.0f;
    int n0 = ch * 32;
    for (int nn = 0; nn < 32; ++nn) {
        int n = n0 + nn;
        float utv[8];
        #pragma unroll
        for (int j = 0; j < 8; ++j) utv[j] = ut[((size_t)n*8 + j)*256 + t];
        const float* Wr = W + ((size_t)c*1152 + n)*128;      // uniform -> s_load
        const float* pr = probs + ((size_t)c*1152 + n)*16;
        #pragma unroll
        for (int i = 0; i < 16; ++i) {
            float wsv = 0.0f;
            #pragma unroll
            for (int j = 0; j < 8; ++j) wsv = fmaf(Wr[i*8 + j], utv[j], wsv);
            float p = uniform ? (1.0f / 1152.0f) : pr[i];
            acc[i] = fmaf(p, wsv, acc[i]);
        }
    }
    #pragma unroll
    for (int i = 0; i < 16; ++i)
        sp[(size_t)ch*40960 + ((size_t)c*16 + i)*256 + t] = acc[i];
}

// -------- reduce partials + routing squash over batch axis ------------------
__global__ __launch_bounds__(256) void sreduce_kernel(
        const float* __restrict__ sp, float* __restrict__ obuf) {
    int ci = blockIdx.x;      // 0..159 = c*16+i
    int t  = threadIdx.x;     // b
    float s = 0.0f;
    for (int ch = 0; ch < 36; ++ch) s += sp[(size_t)ch*40960 + (size_t)ci*256 + t];
    float v = s * s;
    #pragma unroll
    for (int m = 1; m < 64; m <<= 1) v += __shfl_xor(v, m, 64);
    __shared__ float red[4];
    if ((t & 63) == 0) red[t >> 6] = v;
    __syncthreads();
    float total = red[0] + red[1] + red[2] + red[3];
    float sc = total / ((1.0f + total) * sqrtf(total));   // routing squash over b
    obuf[(size_t)ci*256 + t] = sc * s;
}

// -------- delta_b[c,n,i] = sum_b u_hat * outputs ; accumulate into bsum -----
__global__ __launch_bounds__(256) void delta_kernel(
        const float* __restrict__ ut, const float* __restrict__ W,
        const float* __restrict__ obuf, float* __restrict__ bsum, int first) {
    int ch = blockIdx.x;      // 0..35
    int c  = blockIdx.y;      // 0..9
    int t  = threadIdx.x;     // b
    float o16[16];
    #pragma unroll
    for (int i = 0; i < 16; ++i) o16[i] = obuf[((size_t)c*16 + i)*256 + t];
    __shared__ float vbuf[16][257];
    int ri = t >> 4, seg = t & 15;
    int n0 = ch * 32;
    for (int nn = 0; nn < 32; ++nn) {
        int n = n0 + nn;
        float utv[8];
        #pragma unroll
        for (int j = 0; j < 8; ++j) utv[j] = ut[((size_t)n*8 + j)*256 + t];
        const float* Wr = W + ((size_t)c*1152 + n)*128;
        #pragma unroll
        for (int i = 0; i < 16; ++i) {
            float uh = 0.0f;
            #pragma unroll
            for (int j = 0; j < 8; ++j) uh = fmaf(Wr[i*8 + j], utv[j], uh);
            vbuf[i][t] = uh * o16[i];
        }
        __syncthreads();
        float part = 0.0f;
        #pragma unroll
        for (int k = 0; k < 16; ++k) part += vbuf[ri][k*16 + seg];
        #pragma unroll
        for (int m = 1; m < 16; m <<= 1) part += __shfl_xor(part, m, 64);
        if (seg == 0) {
            size_t bi = ((size_t)c*1152 + n)*16 + ri;
            bsum[bi] = first ? part : (bsum[bi] + part);
        }
        __syncthreads();
    }
}

// -------- softmax over the 1152 capsule axis --------------------------------
__global__ __launch_bounds__(256) void softmax_kernel(
        const float* __restrict__ bsum, float* __restrict__ probs) {
    int ci = blockIdx.x;      // c*16+i
    int c = ci >> 4, i = ci & 15;
    int t = threadIdx.x;
    const float* bp = bsum + (size_t)c*1152*16 + i;
    float vals[5];
    float m = -1e30f;
    #pragma unroll
    for (int k = 0; k < 5; ++k) {
        int n = t + k * 256;
        vals[k] = (n < 1152) ? bp[(size_t)n*16] : -1e30f;
        m = fmaxf(m, vals[k]);
    }
    #pragma unroll
    for (int mm = 1; mm < 64; mm <<= 1) m = fmaxf(m, __shfl_xor(m, mm, 64));
    __shared__ float red[4];
    if ((t & 63) == 0) red[t >> 6] = m;
    __syncthreads();
    m = fmaxf(fmaxf(red[0], red[1]), fmaxf(red[2], red[3]));
    __syncthreads();
    float se = 0.0f;
    #pragma unroll
    for (int k = 0; k < 5; ++k) {
        int n = t + k * 256;
        float e = (n < 1152) ? expf(vals[k] - m) : 0.0f;
        vals[k] = e;
        se += e;
    }
    #pragma unroll
    for (int mm = 1; mm < 64; mm <<= 1) se += __shfl_xor(se, mm, 64);
    if ((t & 63) == 0) red[t >> 6] = se;
    __syncthreads();
    se = red[0] + red[1] + red[2] + red[3];
    float inv = 1.0f / se;
    #pragma unroll
    for (int k = 0; k < 5; ++k) {
        int n = t + k * 256;
        if (n < 1152) probs[((size_t)c*1152 + n)*16 + i] = vals[k] * inv;
    }
}

// -------- final: out[b,c] = sum_i outputs[c,i,b]^2 --------------------------
__global__ __launch_bounds__(256) void final_kernel(
        const float* __restrict__ obuf, float* __restrict__ out) {
    int c = blockIdx.x;       // 0..9
    int t = threadIdx.x;      // b
    float s = 0.0f;
    #pragma unroll
    for (int i = 0; i < 16; ++i) {
        float v = obuf[((size_t)c*16 + i)*256 + t];
        s = fmaf(v, v, s);
    }
    out[(size_t)t*10 + c] = s;
}

// ---------------------------------------------------------------------------
extern "C" void kernel_launch(void* const* d_in, const int* in_sizes, int n_in,
                              void* d_out, int out_size, void* d_ws, size_t ws_size,
                              hipStream_t stream) {
    const float* x  = (const float*)d_in[0];
    const float* w1 = (const float*)d_in[1];
    const float* b1 = (const float*)d_in[2];
    const float* w2 = (const float*)d_in[3];
    const float* b2 = (const float*)d_in[4];
    const float* W  = (const float*)d_in[5];
    float* out = (float*)d_out;
    (void)in_sizes; (void)n_in; (void)out_size;

    if (ws_size < B_END) return;   // visible failure if ws too small

    char* wsb = (char*)d_ws;
    unsigned short* qhi = (unsigned short*)(wsb + B_QHI);
    unsigned short* qlo = (unsigned short*)(wsb + B_QLO);
    unsigned short* whi = (unsigned short*)(wsb + B_WHI);
    unsigned short* wlo = (unsigned short*)(wsb + B_WLO);
    float* h2 = (float*)(wsb + B_H2);
    float* ws = (float*)d_ws;
    float* ut = ws + F_UT;
    float* sp = ws + F_SP;
    float* ob = ws + F_OB;
    float* bs = ws + F_BS;
    float* pr = ws + F_PR;

    w2t_kernel<<<dim3(256, 2), 256, 0, stream>>>(w2, whi, wlo);
    conv1_kernel<<<256, 256, 0, stream>>>(x, w1, b1, qhi, qlo);
    conv2_mfma<<<dim3(96, 8), 256, 0, stream>>>(qhi, qlo, whi, wlo, b2, h2);
    squash_t_kernel<<<1152, 256, 0, stream>>>(h2, ut);

    for (int it = 0; it < 3; ++it) {
        if (it > 0) softmax_kernel<<<160, 256, 0, stream>>>(bs, pr);
        spart_kernel<<<dim3(36, 10), 256, 0, stream>>>(ut, W, pr, sp, it == 0 ? 1 : 0);
        sreduce_kernel<<<160, 256, 0, stream>>>(sp, ob);
        if (it < 2) delta_kernel<<<dim3(36, 10), 256, 0, stream>>>(ut, W, ob, bs, it == 0 ? 1 : 0);
    }
    final_kernel<<<10, 256, 0, stream>>>(ob, out);
}

// Round 3
// 791.756 us; speedup vs baseline: 5.0778x; 1.4517x over previous
//
#include <hip/hip_runtime.h>
#include <math.h>

using short8 = __attribute__((ext_vector_type(8))) short;
using f32x4  = __attribute__((ext_vector_type(4))) float;

// ---------------- workspace byte offsets ----------------
static const size_t B_QHI = 0;                  // h1q hi [19*19][b][ci] bf16
static const size_t B_QLO = 47316992;
static const size_t B_WHI = 94633984;           // w2t [k][c][ci] bf16 hi/lo
static const size_t B_WLO = 105250816;
static const size_t B_H2  = 115867648;          // h2t [c*36+p][b] fp32
static const size_t B_END = 125304832;
// routing buffers alias h1q region (dead after conv2) — float offsets
static const size_t F_UT = 0;            // [1152][8][256]
static const size_t F_SP = 2359296;      // [36][160][256]
static const size_t F_OB = 3833856;      // [160][256]
static const size_t F_BS = 3874816;      // [10][1152][16]
static const size_t F_PR = 4059136;      // [10][1152][16]

__device__ __forceinline__ unsigned short bf16_rne(float v) {
    unsigned int u = __builtin_bit_cast(unsigned int, v);
    u += 0x7FFFu + ((u >> 16) & 1u);
    return (unsigned short)(u >> 16);
}
__device__ __forceinline__ float bf16_tof(unsigned short h) {
    unsigned int u = ((unsigned int)h) << 16;
    return __builtin_bit_cast(float, u);
}

// async global->LDS, 16B per lane, dest = uniform base + lane*16
__device__ __forceinline__ void gll16(const unsigned short* g, unsigned short* l) {
    __builtin_amdgcn_global_load_lds(
        (const __attribute__((address_space(1))) unsigned int*)(uintptr_t)g,
        (__attribute__((address_space(3))) unsigned int*)(uintptr_t)l,
        16, 0, 0);
}

// ---------------- conv1: grid (b, x-half), thread = c ----------------------
// 4-wide ox groups: 12 x-values in regs serve 36 FMA (0.33 LDS reads/FMA)
__global__ __launch_bounds__(256) void conv1_kernel(
        const float* __restrict__ x, const float* __restrict__ w1,
        const float* __restrict__ b1,
        unsigned short* __restrict__ qhi, unsigned short* __restrict__ qlo) {
    int b  = blockIdx.x;
    int xh = blockIdx.y;                 // 0: ox 0..9, 1: ox 10..18
    int c  = threadIdx.x;
    __shared__ float xs[28][20];
    for (int i = c; i < 560; i += 256) {
        int row = i / 20, cl = i - row * 20, gc = xh * 10 + cl;
        xs[row][cl] = (gc < 28) ? x[(size_t)b*784 + row*28 + gc] : 0.f;
    }
    float wr[81];
    #pragma unroll
    for (int k = 0; k < 81; ++k) wr[k] = w1[c*81 + k];
    float bias = b1[c];
    __syncthreads();
    for (int oy = 0; oy < 19; ++oy) {
        #pragma unroll
        for (int gx = 0; gx < 3; ++gx) {
            float acc[4] = {0.f, 0.f, 0.f, 0.f};
            for (int ky = 0; ky < 9; ++ky) {
                float xv[12];
                #pragma unroll
                for (int i = 0; i < 12; ++i) xv[i] = xs[oy + ky][gx*4 + i];
                #pragma unroll
                for (int kx = 0; kx < 9; ++kx) {
                    float wv = wr[ky*9 + kx];
                    #pragma unroll
                    for (int e = 0; e < 4; ++e)
                        acc[e] = fmaf(xv[kx + e], wv, acc[e]);
                }
            }
            #pragma unroll
            for (int e = 0; e < 4; ++e) {
                int oxl = gx*4 + e, ox = xh*10 + oxl;
                if (oxl < 10 && ox < 19) {
                    float v = fmaxf(bias + acc[e], 0.f);
                    unsigned short hi = bf16_rne(v);
                    unsigned short lo = bf16_rne(v - bf16_tof(hi));
                    size_t o = ((size_t)(oy*19 + ox)*256 + b)*256 + c;
                    qhi[o] = hi; qlo[o] = lo;
                }
            }
        }
    }
}

// ---------------- w2 transpose+split: [c][ci][81] -> [k][c][ci] hi/lo -------
__global__ __launch_bounds__(256) void w2t_kernel(
        const float* __restrict__ w2,
        unsigned short* __restrict__ whi, unsigned short* __restrict__ wlo) {
    int c    = blockIdx.x;
    int half = blockIdx.y;
    int t = threadIdx.x;
    __shared__ float buf[128*81];
    const float* src = w2 + (size_t)c*20736 + (size_t)half*128*81;
    for (int i = t; i < 128*81; i += 256) buf[i] = src[i];
    __syncthreads();
    int kk = t >> 7, cil = t & 127;
    for (int k2 = 0; k2 < 41; ++k2) {
        int k = k2*2 + kk;
        if (k < 81) {
            float v = buf[cil*81 + k];
            unsigned short hi = bf16_rne(v);
            unsigned short lo = bf16_rne(v - bf16_tof(hi));
            size_t o = ((size_t)k*256 + c)*256 + half*128 + cil;
            whi[o] = hi; wlo[o] = lo;
        }
    }
}

// -------- staging for conv2: wave-role async loads, pre-swizzled source -----
__device__ __forceinline__ void stage_step(
        const unsigned short* __restrict__ qh, const unsigned short* __restrict__ ql_,
        const unsigned short* __restrict__ wh, const unsigned short* __restrict__ wl,
        unsigned short* Ah, unsigned short* Al,
        unsigned short* Bh, unsigned short* Bl,
        int wv, int lane, int qy, int ky, int cis, int bt, int cg) {
    int swz = (((lane & 3) ^ ((lane >> 3) & 3)) << 3);   // src chunk swizzle (elems)
    int r4  = lane >> 2;
    if (wv < 2) {
        const unsigned short* src = wv ? ql_ : qh;
        unsigned short* dst = wv ? Al : Ah;
        size_t base = (((size_t)(qy*19)*256 + bt*16 + r4) << 8) + cis*32 + swz;
        #pragma unroll
        for (int q = 0; q < 19; ++q)
            gll16(src + base + ((size_t)q << 16), dst + q*512);
    } else {
        const unsigned short* src = (wv == 3) ? wl : wh;
        unsigned short* dst = (wv == 3) ? Bl : Bh;
        #pragma unroll
        for (int g = 0; g < 18; ++g) {
            int kx = g >> 1, cl = ((g & 1) << 4) + r4;
            size_t off = ((((size_t)(ky*9 + kx)) * 256 + cg*32 + cl) << 8) + cis*32 + swz;
            gll16(src + off, dst + g*512);
        }
    }
}

// ---------------- conv2: hoisted-fragment single-buffer pipeline ------------
// per K-step: 44 ds_read_b128 -> regs; barrier; async-stage next step; 81 MFMA
// from regs (setprio); barrier (vmcnt drain covered by MFMA phase).
__global__ __launch_bounds__(256) void conv2_mfma(
        const unsigned short* __restrict__ qhi, const unsigned short* __restrict__ qlo,
        const unsigned short* __restrict__ whi, const unsigned short* __restrict__ wlo,
        const float* __restrict__ b2, float* __restrict__ h2t) {
    int bx = blockIdx.x;            // 0..95
    int bt = bx / 6, oy = bx % 6;
    int cg = blockIdx.y;            // 0..7
    int t = threadIdx.x;
    int wv = t >> 6, l = t & 63;
    int mh = wv >> 1, ch = wv & 1;
    int r = l & 15, sl = l >> 4;
    int cs = sl ^ ((r >> 1) & 3);

    __shared__ unsigned short Ah[9728], Al[9728];   // 19*16 rows x 32 ci
    __shared__ unsigned short Bh[9216], Bl[9216];   // 9*32 rows x 32 ci

    f32x4 acc[3];
    #pragma unroll
    for (int i = 0; i < 3; ++i) acc[i] = (f32x4){0.f, 0.f, 0.f, 0.f};

    stage_step(qhi, qlo, whi, wlo, Ah, Al, Bh, Bl, wv, l, oy*2, 0, 0, bt, cg);
    __syncthreads();

    #pragma unroll 1
    for (int step = 0; step < 72; ++step) {
        // ---- fragment reads (all -> registers)
        short8 afh[13], afl[13], bhv[9], blv[9];
        #pragma unroll
        for (int q2 = 0; q2 < 13; ++q2) {
            int off = ((mh*6 + q2)*16 + r)*32 + cs*8;
            afh[q2] = *(const short8*)(Ah + off);
            afl[q2] = *(const short8*)(Al + off);
        }
        #pragma unroll
        for (int kx = 0; kx < 9; ++kx) {
            int boff = (kx*32 + ch*16 + r)*32 + cs*8;
            bhv[kx] = *(const short8*)(Bh + boff);
            blv[kx] = *(const short8*)(Bl + boff);
        }
        __syncthreads();               // all LDS reads done -> buffer free
        if (step < 71) {
            int s1 = step + 1, ky1 = s1 >> 3, cis1 = s1 & 7;
            stage_step(qhi, qlo, whi, wlo, Ah, Al, Bh, Bl,
                       wv, l, oy*2 + ky1, ky1, cis1, bt, cg);
        }
        __builtin_amdgcn_s_setprio(1);
        #pragma unroll
        for (int kx = 0; kx < 9; ++kx) {
            #pragma unroll
            for (int oxl = 0; oxl < 3; ++oxl) {
                int q2 = 2*oxl + kx;
                acc[oxl] = __builtin_amdgcn_mfma_f32_16x16x32_bf16(afh[q2], bhv[kx], acc[oxl], 0, 0, 0);
                acc[oxl] = __builtin_amdgcn_mfma_f32_16x16x32_bf16(afh[q2], blv[kx], acc[oxl], 0, 0, 0);
                acc[oxl] = __builtin_amdgcn_mfma_f32_16x16x32_bf16(afl[q2], bhv[kx], acc[oxl], 0, 0, 0);
            }
        }
        __builtin_amdgcn_s_setprio(0);
        __syncthreads();               // drains vmcnt: next buffer ready
    }

    // ---- epilogue: h2t[(c*36+p)][b], float4 over 4 consecutive b
    int cglob = cg*32 + ch*16 + r;
    float bv = b2[cglob];
    #pragma unroll
    for (int oxl = 0; oxl < 3; ++oxl) {
        int p = oy*6 + mh*3 + oxl;
        float4 o;
        o.x = acc[oxl][0] + bv; o.y = acc[oxl][1] + bv;
        o.z = acc[oxl][2] + bv; o.w = acc[oxl][3] + bv;
        *(float4*)(h2t + (size_t)(cglob*36 + p)*256 + bt*16 + sl*4) = o;
    }
}

// -------- primary squash: h2t[n*8+j][b] -> ut[n][j][b], fully coalesced -----
__global__ __launch_bounds__(256) void squash_t_kernel(
        const float* __restrict__ h2t, float* __restrict__ ut) {
    int n = blockIdx.x;       // 0..1151
    int b = threadIdx.x;      // 0..255
    float v[8];
    float sq = 0.f;
    #pragma unroll
    for (int j = 0; j < 8; ++j) {
        v[j] = h2t[(size_t)(n*8 + j)*256 + b];
        sq = fmaf(v[j], v[j], sq);
    }
    float sc = sq / (1.0f + sq);   // primary squash: NO /sqrt
    #pragma unroll
    for (int j = 0; j < 8; ++j)
        ut[((size_t)n*8 + j)*256 + b] = sc * v[j];
}

// -------- s partials: s[c,i,b] = sum_n probs[c,n,i] * sum_j W*ut ------------
__global__ __launch_bounds__(256) void spart_kernel(
        const float* __restrict__ ut, const float* __restrict__ W,
        const float* __restrict__ probs, float* __restrict__ sp, int uniform) {
    int ch = blockIdx.x;      // 0..35 (n-chunks of 32)
    int c  = blockIdx.y;      // 0..9
    int t  = threadIdx.x;     // b
    float acc[16];
    #pragma unroll
    for (int i = 0; i < 16; ++i) acc[i] = 0.0f;
    int n0 = ch * 32;
    for (int nn = 0; nn < 32; ++nn) {
        int n = n0 + nn;
        float utv[8];
        #pragma unroll
        for (int j = 0; j < 8; ++j) utv[j] = ut[((size_t)n*8 + j)*256 + t];
        const float* Wr = W + ((size_t)c*1152 + n)*128;
        const float* pr = probs + ((size_t)c*1152 + n)*16;
        #pragma unroll
        for (int i = 0; i < 16; ++i) {
            float wsv = 0.0f;
            #pragma unroll
            for (int j = 0; j < 8; ++j) wsv = fmaf(Wr[i*8 + j], utv[j], wsv);
            float p = uniform ? (1.0f / 1152.0f) : pr[i];
            acc[i] = fmaf(p, wsv, acc[i]);
        }
    }
    #pragma unroll
    for (int i = 0; i < 16; ++i)
        sp[(size_t)ch*40960 + ((size_t)c*16 + i)*256 + t] = acc[i];
}

// -------- reduce partials + routing squash over batch axis ------------------
__global__ __launch_bounds__(256) void sreduce_kernel(
        const float* __restrict__ sp, float* __restrict__ obuf) {
    int ci = blockIdx.x;      // 0..159 = c*16+i
    int t  = threadIdx.x;     // b
    float s = 0.0f;
    for (int ch = 0; ch < 36; ++ch) s += sp[(size_t)ch*40960 + (size_t)ci*256 + t];
    float v = s * s;
    #pragma unroll
    for (int m = 1; m < 64; m <<= 1) v += __shfl_xor(v, m, 64);
    __shared__ float red[4];
    if ((t & 63) == 0) red[t >> 6] = v;
    __syncthreads();
    float total = red[0] + red[1] + red[2] + red[3];
    float sc = total / ((1.0f + total) * sqrtf(total));
    obuf[(size_t)ci*256 + t] = sc * s;
}

// -------- delta_b[c,n,i] = sum_b u_hat * outputs ; accumulate into bsum -----
__global__ __launch_bounds__(256) void delta_kernel(
        const float* __restrict__ ut, const float* __restrict__ W,
        const float* __restrict__ obuf, float* __restrict__ bsum, int first) {
    int ch = blockIdx.x;      // 0..35
    int c  = blockIdx.y;      // 0..9
    int t  = threadIdx.x;     // b
    float o16[16];
    #pragma unroll
    for (int i = 0; i < 16; ++i) o16[i] = obuf[((size_t)c*16 + i)*256 + t];
    __shared__ float vbuf[16][257];
    int ri = t >> 4, seg = t & 15;
    int n0 = ch * 32;
    for (int nn = 0; nn < 32; ++nn) {
        int n = n0 + nn;
        float utv[8];
        #pragma unroll
        for (int j = 0; j < 8; ++j) utv[j] = ut[((size_t)n*8 + j)*256 + t];
        const float* Wr = W + ((size_t)c*1152 + n)*128;
        #pragma unroll
        for (int i = 0; i < 16; ++i) {
            float uh = 0.0f;
            #pragma unroll
            for (int j = 0; j < 8; ++j) uh = fmaf(Wr[i*8 + j], utv[j], uh);
            vbuf[i][t] = uh * o16[i];
        }
        __syncthreads();
        float part = 0.0f;
        #pragma unroll
        for (int k = 0; k < 16; ++k) part += vbuf[ri][k*16 + seg];
        #pragma unroll
        for (int m = 1; m < 16; m <<= 1) part += __shfl_xor(part, m, 64);
        if (seg == 0) {
            size_t bi = ((size_t)c*1152 + n)*16 + ri;
            bsum[bi] = first ? part : (bsum[bi] + part);
        }
        __syncthreads();
    }
}

// -------- softmax over the 1152 capsule axis --------------------------------
__global__ __launch_bounds__(256) void softmax_kernel(
        const float* __restrict__ bsum, float* __restrict__ probs) {
    int ci = blockIdx.x;      // c*16+i
    int c = ci >> 4, i = ci & 15;
    int t = threadIdx.x;
    const float* bp = bsum + (size_t)c*1152*16 + i;
    float vals[5];
    float m = -1e30f;
    #pragma unroll
    for (int k = 0; k < 5; ++k) {
        int n = t + k * 256;
        vals[k] = (n < 1152) ? bp[(size_t)n*16] : -1e30f;
        m = fmaxf(m, vals[k]);
    }
    #pragma unroll
    for (int mm = 1; mm < 64; mm <<= 1) m = fmaxf(m, __shfl_xor(m, mm, 64));
    __shared__ float red[4];
    if ((t & 63) == 0) red[t >> 6] = m;
    __syncthreads();
    m = fmaxf(fmaxf(red[0], red[1]), fmaxf(red[2], red[3]));
    __syncthreads();
    float se = 0.0f;
    #pragma unroll
    for (int k = 0; k < 5; ++k) {
        int n = t + k * 256;
        float e = (n < 1152) ? expf(vals[k] - m) : 0.0f;
        vals[k] = e;
        se += e;
    }
    #pragma unroll
    for (int mm = 1; mm < 64; mm <<= 1) se += __shfl_xor(se, mm, 64);
    if ((t & 63) == 0) red[t >> 6] = se;
    __syncthreads();
    se = red[0] + red[1] + red[2] + red[3];
    float inv = 1.0f / se;
    #pragma unroll
    for (int k = 0; k < 5; ++k) {
        int n = t + k * 256;
        if (n < 1152) probs[((size_t)c*1152 + n)*16 + i] = vals[k] * inv;
    }
}

// -------- final: out[b,c] = sum_i outputs[c,i,b]^2 --------------------------
__global__ __launch_bounds__(256) void final_kernel(
        const float* __restrict__ obuf, float* __restrict__ out) {
    int c = blockIdx.x;       // 0..9
    int t = threadIdx.x;      // b
    float s = 0.0f;
    #pragma unroll
    for (int i = 0; i < 16; ++i) {
        float v = obuf[((size_t)c*16 + i)*256 + t];
        s = fmaf(v, v, s);
    }
    out[(size_t)t*10 + c] = s;
}

// ---------------------------------------------------------------------------
extern "C" void kernel_launch(void* const* d_in, const int* in_sizes, int n_in,
                              void* d_out, int out_size, void* d_ws, size_t ws_size,
                              hipStream_t stream) {
    const float* x  = (const float*)d_in[0];
    const float* w1 = (const float*)d_in[1];
    const float* b1 = (const float*)d_in[2];
    const float* w2 = (const float*)d_in[3];
    const float* b2 = (const float*)d_in[4];
    const float* W  = (const float*)d_in[5];
    float* out = (float*)d_out;
    (void)in_sizes; (void)n_in; (void)out_size;

    if (ws_size < B_END) return;

    char* wsb = (char*)d_ws;
    unsigned short* qhi = (unsigned short*)(wsb + B_QHI);
    unsigned short* qlo = (unsigned short*)(wsb + B_QLO);
    unsigned short* whi = (unsigned short*)(wsb + B_WHI);
    unsigned short* wlo = (unsigned short*)(wsb + B_WLO);
    float* h2t = (float*)(wsb + B_H2);
    float* ws = (float*)d_ws;
    float* ut = ws + F_UT;
    float* sp = ws + F_SP;
    float* ob = ws + F_OB;
    float* bs = ws + F_BS;
    float* pr = ws + F_PR;

    w2t_kernel<<<dim3(256, 2), 256, 0, stream>>>(w2, whi, wlo);
    conv1_kernel<<<dim3(256, 2), 256, 0, stream>>>(x, w1, b1, qhi, qlo);
    conv2_mfma<<<dim3(96, 8), 256, 0, stream>>>(qhi, qlo, whi, wlo, b2, h2t);
    squash_t_kernel<<<1152, 256, 0, stream>>>(h2t, ut);

    for (int it = 0; it < 3; ++it) {
        if (it > 0) softmax_kernel<<<160, 256, 0, stream>>>(bs, pr);
        spart_kernel<<<dim3(36, 10), 256, 0, stream>>>(ut, W, pr, sp, it == 0 ? 1 : 0);
        sreduce_kernel<<<160, 256, 0, stream>>>(sp, ob);
        if (it < 2) delta_kernel<<<dim3(36, 10), 256, 0, stream>>>(ut, W, ob, bs, it == 0 ? 1 : 0);
    }
    final_kernel<<<10, 256, 0, stream>>>(ob, out);
}